// Round 8
// baseline (115.892 us; speedup 1.0000x reference)
//
#include <hip/hip_runtime.h>

// CostVolume: out (1, 2C, D4, H, W) fp32
//   c <  C : left [c,h,w]     if w >= d else 0
//   c >= C : right[c-C,h,w-d] if w >= d else 0
// C=32, H=128, W=240, D4=48.  Write-BW-bound: 377.5 MB out.
//
// DIAGNOSTIC ROUND (slope test): R3/R5/R6/R7 all sit at 4.87 TB/s across
// wildly different write organizations; fill demonstrates 6.9 TB/s. This
// kernel stores the output TWICE (identical values; barrier + memory clobber
// between passes). Marginal rate = 377.5MB / (dur - 77.6us):
//   dur ~132us -> fixed per-replay overhead ~22us, kernel at fill roofline.
//   dur ~155us -> genuine ~4.9 TB/s kernel ceiling, keep investigating.

constexpr int C   = 32;
constexpr int H   = 128;
constexpr int W   = 240;
constexpr int D4  = 48;
constexpr int W4  = W / 4;            // 60 float4 per row
constexpr int RPB = 8;                // rows per block
constexpr int HC  = H / RPB;          // 16 h-chunks
constexpr int CH4 = RPB * W4;         // 480 float4 per chunk
constexpr int BLOCK = 256;
constexpr int PAD_OFF = 48;           // guard so (w - d) reads stay >= 0

typedef float f32x4 __attribute__((ext_vector_type(4)));

__device__ __forceinline__ int pidx(int x) { return x + (x >> 5); }

__global__ void __launch_bounds__(256) cost_volume_kernel(
    const float* __restrict__ left,
    const float* __restrict__ right,
    float* __restrict__ out) {
    __shared__ float rowbuf[2080];

    const int blk = blockIdx.x;        // c2*HC + hc
    const int hc  = blk % HC;
    const int c2  = blk / HC;
    const int h0  = hc * RPB;
    const int tid = threadIdx.x;
    const bool is_left = (c2 < C);

    f32x4* __restrict__ outb = reinterpret_cast<f32x4*>(out)
        + ((long)(c2 * D4) * H + h0) * W4;
    const long dstride = (long)H * W4;

    const int f0  = tid;
    const int f1  = tid + BLOCK;
    const bool has1 = (f1 < CH4);
    const int f1c = has1 ? f1 : (CH4 - 1);
    const int w0_0 = (f0 % W4) * 4;
    const int w0_1 = (f1c % W4) * 4;

    if (is_left) {
        const f32x4* __restrict__ src4 =
            reinterpret_cast<const f32x4*>(left + (c2 * H + h0) * W);
        const f32x4 t0 = src4[f0];
        const f32x4 t1 = has1 ? src4[f1] : f32x4{0.f, 0.f, 0.f, 0.f};
#pragma unroll 1
        for (int rep = 0; rep < 2; ++rep) {
#pragma unroll 4
            for (int d = 0; d < D4; ++d) {
                f32x4 v0, v1;
#pragma unroll
                for (int j = 0; j < 4; ++j) {
                    v0[j] = (w0_0 + j >= d) ? t0[j] : 0.0f;
                    v1[j] = (w0_1 + j >= d) ? t1[j] : 0.0f;
                }
                f32x4* __restrict__ o = outb + d * dstride;
                o[f0] = v0;
                if (has1) o[f1] = v1;
            }
            __syncthreads();
            asm volatile("" ::: "memory");   // block DSE of pass-1 stores
        }
    } else {
        const float* __restrict__ src = right + ((c2 - C) * H + h0) * W;
        for (int f = tid; f < CH4; f += BLOCK) {
            f32x4 t = reinterpret_cast<const f32x4*>(src)[f];
            const int base = PAD_OFF + f * 4;
#pragma unroll
            for (int j = 0; j < 4; ++j) rowbuf[pidx(base + j)] = t[j];
        }
        __syncthreads();
        const int b0 = PAD_OFF + (f0  / W4) * W + w0_0;
        const int b1 = PAD_OFF + (f1c / W4) * W + w0_1;
#pragma unroll 1
        for (int rep = 0; rep < 2; ++rep) {
#pragma unroll 4
            for (int d = 0; d < D4; ++d) {
                f32x4 v0, v1;
#pragma unroll
                for (int j = 0; j < 4; ++j) {
                    v0[j] = (w0_0 + j >= d) ? rowbuf[pidx(b0 - d + j)] : 0.0f;
                    v1[j] = (w0_1 + j >= d) ? rowbuf[pidx(b1 - d + j)] : 0.0f;
                }
                f32x4* __restrict__ o = outb + d * dstride;
                o[f0] = v0;
                if (has1) o[f1] = v1;
            }
            __syncthreads();
            asm volatile("" ::: "memory");   // block DSE of pass-1 stores
        }
    }
}

extern "C" void kernel_launch(void* const* d_in, const int* in_sizes, int n_in,
                              void* d_out, int out_size, void* d_ws,
                              size_t ws_size, hipStream_t stream) {
    const float* left  = (const float*)d_in[0];
    const float* right = (const float*)d_in[1];
    float* out = (float*)d_out;

    const int grid = 2 * C * HC;   // 1024 blocks
    cost_volume_kernel<<<grid, BLOCK, 0, stream>>>(left, right, out);
}

// Round 9
// 105.097 us; speedup vs baseline: 1.1027x; 1.1027x over previous
//
#include <hip/hip_runtime.h>

// CostVolume: out (1, 2C, D4, H, W) fp32
//   c <  C : left [c,h,w]     if w >= d else 0
//   c >= C : right[c-C,h,w-d] if w >= d else 0
// C=32, H=128, W=240, D4=48.  Write-BW-bound: 377.5 MB out.
//
// R8 slope test: issue machinery does a full extra store pass in 38us ->
// kernel is drain-limited. Last untested axis: device-linear write order
// (R4 had it but confounded with scalar gather reads; 89.6us). This round:
// one block per (c2,d) slice = 122,880B contiguous writes, XCD-swizzled so
// each XCD writes one contiguous 47MB region and its 8 source images stay
// L2-resident; right-path reads are single unaligned float4 loads (uniform
// shift d), not scalar gathers.

constexpr int C      = 32;
constexpr int H      = 128;
constexpr int W      = 240;
constexpr int D4     = 48;
constexpr int W4     = W / 4;          // 60 float4 per row
constexpr int SLICE4 = H * W4;         // 7680 float4 per (c2,d) slice
constexpr int BLOCK  = 256;
constexpr int ITERS  = SLICE4 / BLOCK; // 30, exact
constexpr int NXCD   = 8;
constexpr int SLICES = 2 * C * D4;     // 3072
constexpr int PER_XCD = SLICES / NXCD; // 384

typedef float f32x4 __attribute__((ext_vector_type(4)));

__global__ void __launch_bounds__(256) cost_volume_kernel(
    const float* __restrict__ left,
    const float* __restrict__ right,
    float* __restrict__ out) {
    // XCD swizzle: blocks round-robin XCDs (bid%8 = XCD). Give XCD x the
    // contiguous slice range [x*384, (x+1)*384): linear writes per XCD,
    // and its 8 source images (960KB) stay L2-resident across 48 d each.
    const int bid   = blockIdx.x;
    const int slice = (bid & (NXCD - 1)) * PER_XCD + (bid >> 3);
    const int d     = slice % D4;       // uniform per block
    const int c2    = slice / D4;
    const bool is_left = (c2 < C);

    f32x4* __restrict__ out4 =
        reinterpret_cast<f32x4*>(out) + (long)slice * SLICE4;
    const int tid = threadIdx.x;

    if (is_left) {
        // left: source float4 layout == output slice layout.
        const f32x4* __restrict__ src4 =
            reinterpret_cast<const f32x4*>(left + c2 * H * W);
#pragma unroll 6
        for (int it = 0; it < ITERS; ++it) {
            const int flat = it * BLOCK + tid;
            const int w0   = (flat % W4) * 4;
            f32x4 v = src4[flat];
            if (w0 < d) {               // only w4 < 12 ever masked
#pragma unroll
                for (int j = 0; j < 4; ++j)
                    if (w0 + j < d) v[j] = 0.0f;
            }
            out4[flat] = v;
        }
    } else {
        // right: value = right[c2-C,h,w-d], shift d block-uniform.
        // Main case (w0 >= d): ONE unaligned float4 load row[w0-d .. w0-d+3],
        // always in-bounds (0 <= w0-d, w0-d+3 <= 239). Edge case (w0 < d,
        // only w4 < 12): aligned load of row[0..3] + lane-local select.
        const float* __restrict__ src = right + (c2 - C) * H * W;
#pragma unroll 6
        for (int it = 0; it < ITERS; ++it) {
            const int flat = it * BLOCK + tid;
            const int h    = flat / W4;
            const int w0   = (flat % W4) * 4;
            const float* __restrict__ row = src + h * W;
            f32x4 v;
            if (w0 >= d) {
                v = *reinterpret_cast<const f32x4*>(row + (w0 - d));
            } else {
                const f32x4 L = *reinterpret_cast<const f32x4*>(row);
#pragma unroll
                for (int j = 0; j < 4; ++j) {
                    const int ii = w0 + j - d;   // needed src idx, in [0,3)
                    v[j] = (ii >= 0) ? L[ii & 3] : 0.0f;
                }
            }
            out4[flat] = v;
        }
    }
}

extern "C" void kernel_launch(void* const* d_in, const int* in_sizes, int n_in,
                              void* d_out, int out_size, void* d_ws,
                              size_t ws_size, hipStream_t stream) {
    const float* left  = (const float*)d_in[0];
    const float* right = (const float*)d_in[1];
    float* out = (float*)d_out;

    cost_volume_kernel<<<SLICES, BLOCK, 0, stream>>>(left, right, out);
}